// Round 1
// baseline (3919.696 us; speedup 1.0000x reference)
//
#include <hip/hip_runtime.h>

#define DIM 16
#define HID 256
#define NSTEPS 10
#define TILE_B 16
#define NTHR 256
#define LSTR 260   // 256 + 4 pad

__device__ __forceinline__ void silu_both(float x, float& h, float& d) {
    float s = 1.0f / (1.0f + __expf(-x));
    h = x * s;
    d = s * (1.0f + x * (1.0f - s));
}

// M[j][k] = W2[j][k] * sum_i W1[i][j] * W3[k][i]   (256x256, constant per launch)
__global__ void cnf_make_M(const float* __restrict__ W1, const float* __restrict__ W2,
                           const float* __restrict__ W3, float* __restrict__ M) {
    const int j = blockIdx.x;
    const int k = threadIdx.x;
    float g = 0.0f;
#pragma unroll
    for (int i = 0; i < DIM; ++i) g = fmaf(W1[i * HID + j], W3[k * DIM + i], g);
    M[j * HID + k] = W2[j * HID + k] * g;
}

__global__ __launch_bounds__(NTHR, 2) void cnf_main(
    const float* __restrict__ x,
    const float* __restrict__ W1, const float* __restrict__ b1,
    const float* __restrict__ W2, const float* __restrict__ b2,
    const float* __restrict__ W3, const float* __restrict__ b3,
    const float* __restrict__ M, float* __restrict__ out)
{
    __shared__ float h1s[TILE_B][LSTR];
    __shared__ float d1s[TILE_B][LSTR];
    __shared__ float h2s[TILE_B][LSTR];
    __shared__ float zstage[TILE_B][DIM];
    __shared__ float zbase[TILE_B][DIM];
    __shared__ float zacc[TILE_B][DIM];
    __shared__ float fzs[TILE_B][DIM];
    __shared__ float divs[TILE_B];
    __shared__ float laccs[TILE_B];
    __shared__ float logps[TILE_B];

    const int tid = (int)threadIdx.x;
    const int b0 = (int)blockIdx.x * TILE_B;
    const int rA = tid >> 4;          // 0..15   (row for DIM-wide ops)
    const int cA = tid & 15;          // 0..15
    const int r0 = (tid >> 6) << 2;   // 0,4,8,12  (wave -> 4-row group)
    const int c0 = (tid & 63) << 2;   // 0..252    (lane -> 4-col group)

    {
        float v = x[(b0 + rA) * DIM + cA];
        zstage[rA][cA] = v;
        zbase[rA][cA] = v;
        if (cA == 0) logps[rA] = 0.0f;
    }

    const float dt = 0.1f;
    const float dt6 = dt / 6.0f;

    for (int step = 0; step < NSTEPS; ++step) {
        const float t0 = dt * (float)step;
        zacc[rA][cA] = 0.0f;
        if (cA == 0) laccs[rA] = 0.0f;

        for (int s = 0; s < 4; ++s) {
            const float t = t0 + ((s == 0) ? 0.0f : (s == 3) ? dt : 0.5f * dt);
            const float wst = (s == 1 || s == 2) ? 2.0f : 1.0f;
            __syncthreads();   // zstage ready, h1s/d1s free for overwrite

            // ---------- phase 1: pre1 = [z, t] @ W1 + b1 -> h1 (silu), d1 (silu') ----------
            {
                float zr[DIM];
#pragma unroll
                for (int i = 0; i < DIM; ++i) zr[i] = zstage[rA][i];
                const int cb = cA << 4;
#pragma unroll
                for (int cc = 0; cc < 16; cc += 4) {
                    const int c = cb + cc;
                    float4 acc = *(const float4*)(b1 + c);
                    const float4 wt = *(const float4*)(W1 + DIM * HID + c);  // t row
                    acc.x = fmaf(t, wt.x, acc.x); acc.y = fmaf(t, wt.y, acc.y);
                    acc.z = fmaf(t, wt.z, acc.z); acc.w = fmaf(t, wt.w, acc.w);
#pragma unroll
                    for (int i = 0; i < DIM; ++i) {
                        const float4 wv = *(const float4*)(W1 + i * HID + c);
                        acc.x = fmaf(zr[i], wv.x, acc.x); acc.y = fmaf(zr[i], wv.y, acc.y);
                        acc.z = fmaf(zr[i], wv.z, acc.z); acc.w = fmaf(zr[i], wv.w, acc.w);
                    }
                    float4 hv, dv;
                    silu_both(acc.x, hv.x, dv.x); silu_both(acc.y, hv.y, dv.y);
                    silu_both(acc.z, hv.z, dv.z); silu_both(acc.w, hv.w, dv.w);
                    *(float4*)&h1s[rA][c] = hv;
                    *(float4*)&d1s[rA][c] = dv;
                }
            }
            __syncthreads();   // h1s/d1s ready

            // ---------- phase 2a: pre2 = h1 @ W2 + b2 -> h2 (LDS), d2 (registers) ----------
            float d2r[4][4];
            {
                float acc[4][4];
                {
                    const float4 bb = *(const float4*)(b2 + c0);
#pragma unroll
                    for (int rr = 0; rr < 4; ++rr) {
                        acc[rr][0] = bb.x; acc[rr][1] = bb.y; acc[rr][2] = bb.z; acc[rr][3] = bb.w;
                    }
                }
                for (int k = 0; k < HID; k += 4) {
                    float a[4][4];
#pragma unroll
                    for (int rr = 0; rr < 4; ++rr)
                        *(float4*)&a[rr][0] = *(const float4*)&h1s[r0 + rr][k];   // broadcast reads
#pragma unroll
                    for (int kk = 0; kk < 4; ++kk) {
                        const float4 wv = *(const float4*)(W2 + (k + kk) * HID + c0);
#pragma unroll
                        for (int rr = 0; rr < 4; ++rr) {
                            acc[rr][0] = fmaf(a[rr][kk], wv.x, acc[rr][0]);
                            acc[rr][1] = fmaf(a[rr][kk], wv.y, acc[rr][1]);
                            acc[rr][2] = fmaf(a[rr][kk], wv.z, acc[rr][2]);
                            acc[rr][3] = fmaf(a[rr][kk], wv.w, acc[rr][3]);
                        }
                    }
                }
#pragma unroll
                for (int rr = 0; rr < 4; ++rr) {
                    float4 hv;
                    silu_both(acc[rr][0], hv.x, d2r[rr][0]);
                    silu_both(acc[rr][1], hv.y, d2r[rr][1]);
                    silu_both(acc[rr][2], hv.z, d2r[rr][2]);
                    silu_both(acc[rr][3], hv.w, d2r[rr][3]);
                    *(float4*)&h2s[r0 + rr][c0] = hv;
                }
            }

            // ---------- phase 2b: v = d1 @ M ; div = sum(v * d2) (d2 still in regs) ----------
            {
                float acc[4][4];
#pragma unroll
                for (int rr = 0; rr < 4; ++rr)
                    acc[rr][0] = acc[rr][1] = acc[rr][2] = acc[rr][3] = 0.0f;
                for (int k = 0; k < HID; k += 4) {
                    float a[4][4];
#pragma unroll
                    for (int rr = 0; rr < 4; ++rr)
                        *(float4*)&a[rr][0] = *(const float4*)&d1s[r0 + rr][k];
#pragma unroll
                    for (int kk = 0; kk < 4; ++kk) {
                        const float4 wv = *(const float4*)(M + (k + kk) * HID + c0);
#pragma unroll
                        for (int rr = 0; rr < 4; ++rr) {
                            acc[rr][0] = fmaf(a[rr][kk], wv.x, acc[rr][0]);
                            acc[rr][1] = fmaf(a[rr][kk], wv.y, acc[rr][1]);
                            acc[rr][2] = fmaf(a[rr][kk], wv.z, acc[rr][2]);
                            acc[rr][3] = fmaf(a[rr][kk], wv.w, acc[rr][3]);
                        }
                    }
                }
                float p[4];
#pragma unroll
                for (int rr = 0; rr < 4; ++rr)
                    p[rr] = acc[rr][0] * d2r[rr][0] + acc[rr][1] * d2r[rr][1]
                          + acc[rr][2] * d2r[rr][2] + acc[rr][3] * d2r[rr][3];
#pragma unroll
                for (int m = 32; m >= 1; m >>= 1) {
#pragma unroll
                    for (int rr = 0; rr < 4; ++rr) p[rr] += __shfl_xor(p[rr], m, 64);
                }
                if ((tid & 63) == 0) {
#pragma unroll
                    for (int rr = 0; rr < 4; ++rr) divs[r0 + rr] = p[rr];
                }
            }
            __syncthreads();   // h2s, divs ready

            // ---------- phase 3: fz = h2 @ W3 + b3 ----------
            {
                float acc = b3[cA];
                for (int k = 0; k < HID; k += 4) {
                    const float4 hv = *(const float4*)&h2s[rA][k];
                    acc = fmaf(hv.x, W3[(k + 0) * DIM + cA], acc);
                    acc = fmaf(hv.y, W3[(k + 1) * DIM + cA], acc);
                    acc = fmaf(hv.z, W3[(k + 2) * DIM + cA], acc);
                    acc = fmaf(hv.w, W3[(k + 3) * DIM + cA], acc);
                }
                fzs[rA][cA] = acc;
            }
            __syncthreads();   // fzs ready (divs had 1 extra sync of margin)

            // ---------- RK4 stage update ----------
            {
                const float fv = fzs[rA][cA];
                const float za = zacc[rA][cA] + wst * fv;
                zacc[rA][cA] = za;
                if (cA == 0) laccs[rA] -= wst * divs[rA];
                if (s < 3) {
                    const float coef = (s == 2) ? dt : 0.5f * dt;
                    zstage[rA][cA] = zbase[rA][cA] + coef * fv;
                } else {
                    const float zn = zbase[rA][cA] + dt6 * za;
                    zbase[rA][cA] = zn;
                    zstage[rA][cA] = zn;
                    if (cA == 0) logps[rA] += dt6 * laccs[rA];
                }
            }
        }
    }

    __syncthreads();
    if (tid < TILE_B) {
        float ss = 0.0f;
#pragma unroll
        for (int i = 0; i < DIM; ++i) { const float zv = zbase[tid][i]; ss = fmaf(zv, zv, ss); }
        out[b0 + tid] = -0.5f * (ss + (float)DIM * 1.8378770664093453f) - logps[tid];
    }
}

extern "C" void kernel_launch(void* const* d_in, const int* in_sizes, int n_in,
                              void* d_out, int out_size, void* d_ws, size_t ws_size,
                              hipStream_t stream) {
    (void)in_sizes; (void)n_in; (void)out_size; (void)ws_size;
    const float* x  = (const float*)d_in[0];
    const float* W1 = (const float*)d_in[1];
    const float* b1 = (const float*)d_in[2];
    const float* W2 = (const float*)d_in[3];
    const float* b2 = (const float*)d_in[4];
    const float* W3 = (const float*)d_in[5];
    const float* b3 = (const float*)d_in[6];
    float* M = (float*)d_ws;   // 256*256*4 = 256 KB scratch

    cnf_make_M<<<HID, HID, 0, stream>>>(W1, W2, W3, M);
    cnf_main<<<8192 / TILE_B, NTHR, 0, stream>>>(x, W1, b1, W2, b2, W3, b3, M, (float*)d_out);
}